// Round 2
// baseline (34736.050 us; speedup 1.0000x reference)
//
#include <hip/hip_runtime.h>
#include <hip/hip_bf16.h>
#include <hip/hip_fp16.h>

// Problem: S,B,E,H,V,O = 1024,256,128,256,32000,2
#define S_LEN 1024
#define BATCH 256
#define EDIM  128
#define HDIM  256
#define ODIM  2

typedef unsigned int uint32;
typedef _Float16 half_t;
typedef half_t half2v __attribute__((ext_vector_type(2)));

// ---------------- ws layout (uint32 units) ----------------
// whhP: [4 q][256 rows'][132]   f16 pairs, LDS image. row' = g*64 + u'*32 + rg
// wihP: [4 q][32 rg][16 kq][8 j][4 pp]
// biasc: 1024 floats
// hbuf: [2 parity][64 cluster][4 b][128 pair]
// ctrs: 64 clusters * 16-int spacing
#define WHH_Q_SZ   (256 * 132)          // 33792
#define OFF_WHH    0
#define OFF_WIH    (4 * WHH_Q_SZ)       // 135168
#define OFF_BIAS   (OFF_WIH + 65536)    // 200704
#define OFF_HBUF   (OFF_BIAS + 1024)    // 201728
#define OFF_CTR    (OFF_HBUF + 65536)   // 267264

__device__ __forceinline__ float sigf(float x)     { return 1.0f / (1.0f + __expf(-x)); }
__device__ __forceinline__ float tanhfast(float x) { return 1.0f - 2.0f / (__expf(2.0f * x) + 1.0f); }

__device__ __forceinline__ uint32 packh2(float a, float b) {
  union { uint32 u; half2v h; } c; c.h[0] = (half_t)a; c.h[1] = (half_t)b; return c.u;
}
__device__ __forceinline__ half2v u2h(uint32 u) {
  union { uint32 u; half2v h; } c; c.u = u; return c.h;
}

#if defined(__has_builtin)
#if __has_builtin(__builtin_amdgcn_fdot2)
#define HAVE_FDOT2 1
#endif
#endif

__device__ __forceinline__ float dot2f(float acc, uint32 w, uint32 x) {
#ifdef HAVE_FDOT2
  return __builtin_amdgcn_fdot2(u2h(w), u2h(x), acc, false);
#else
  half2v a = u2h(w), b = u2h(x);
  acc = fmaf((float)a[0], (float)b[0], acc);
  return fmaf((float)a[1], (float)b[1], acc);
#endif
}

// sum across the 16-lane DPP row; all 16 lanes receive the total
__device__ __forceinline__ float rowsum16(float v) {
  v += __int_as_float(__builtin_amdgcn_update_dpp(0, __float_as_int(v), 0x128, 0xf, 0xf, true)); // row_ror:8
  v += __int_as_float(__builtin_amdgcn_update_dpp(0, __float_as_int(v), 0x124, 0xf, 0xf, true)); // row_ror:4
  v += __int_as_float(__builtin_amdgcn_update_dpp(0, __float_as_int(v), 0x122, 0xf, 0xf, true)); // row_ror:2
  v += __int_as_float(__builtin_amdgcn_update_dpp(0, __float_as_int(v), 0x121, 0xf, 0xf, true)); // row_ror:1
  return v;
}

// ---------------- prep: pack weights f16, fold bias, zero barriers ----------------
__global__ void prep_kernel(const float* __restrict__ w_ih, const float* __restrict__ w_hh,
                            const float* __restrict__ b_ih, const float* __restrict__ b_hh,
                            uint32* __restrict__ ws_u) {
  uint32* whhP = ws_u + OFF_WHH;
  uint32* wihP = ws_u + OFF_WIH;
  float*  biasc = (float*)(ws_u + OFF_BIAS);
  int*    ctrs  = (int*)(ws_u + OFF_CTR);
  int id = blockIdx.x * 256 + threadIdx.x;
  if (id < 131072) {                          // whh: 4q * 256r * 128p
    int q = id >> 15, rem = id & 32767;
    int r = rem >> 7, p = rem & 127;
    int g = r >> 6, lu = r & 63;
    int rp = g * 64 + (lu & 1) * 32 + (lu >> 1);
    int orig = g * 256 + q * 64 + lu;
    whhP[q * WHH_Q_SZ + rp * 132 + p] = packh2(w_hh[orig * HDIM + 2 * p], w_hh[orig * HDIM + 2 * p + 1]);
  } else if (id < 131072 + 65536) {           // wih
    int id2 = id - 131072;
    int q = id2 >> 14, rem = id2 & 16383;
    int rg = rem >> 9, kq = (rem >> 5) & 15, j = (rem >> 2) & 7, pp = rem & 3;
    int g = j >> 1, up = j & 1;
    int lu = 2 * rg + up;
    int orig = g * 256 + q * 64 + lu;
    int k = (kq * 4 + pp) * 2;
    wihP[(((q * 32 + rg) * 16 + kq) * 8 + j) * 4 + pp] =
        packh2(w_ih[orig * EDIM + k], w_ih[orig * EDIM + k + 1]);
  } else if (id < 131072 + 65536 + 1024) {
    int i = id - 131072 - 65536;
    biasc[i] = b_ih[i] + b_hh[i];
  } else if (id < 131072 + 65536 + 1024 + 64) {
    ctrs[(id - 131072 - 65536 - 1024) * 16] = 0;
  }
}

// ---------------- LSTM: 4-block clusters, LDS-resident W_hh ----------------
// blockIdx: cluster c = bid>>2 (4 batch cols: 4c..4c+3), q = bid&3 (hidden units 64q..64q+64)
// thread: rg = tid>>4 (unit pair 2rg,2rg+1), kq = tid&15 (k-slice). DPP row == one rg's 16 kq lanes.
__global__ __launch_bounds__(512, 2) void lstm_kernel(
    const int* __restrict__ inp, const int* __restrict__ lengths,
    const float* __restrict__ h0, const float* __restrict__ c0,
    const float* __restrict__ emb, uint32* __restrict__ ws_u,
    float* __restrict__ outh, float* __restrict__ outc) {
  __shared__ uint32 whh_l[WHH_Q_SZ];     // 135168 B
  __shared__ uint32 h_l[4 * 132];        // 2112 B  [b][pair], stride 132
  __shared__ uint32 x_l[2 * 256];        // 2048 B  [parity][b][pair(64)]

  const int tid = threadIdx.x;
  const int q = blockIdx.x & 3;
  const int c = blockIdx.x >> 2;
  const int rg = tid >> 4, kq = tid & 15;

  const uint32* whhP = ws_u + OFF_WHH + q * WHH_Q_SZ;
  const uint32* wihP = ws_u + OFF_WIH;
  const float*  biasc = (const float*)(ws_u + OFF_BIAS);
  uint32* hbuf = ws_u + OFF_HBUF;
  int*    ctr  = (int*)(ws_u + OFF_CTR) + c * 16;

  // load W_hh slice into LDS (once)
  {
    const uint4* src = (const uint4*)whhP;
    uint4* dst = (uint4*)whh_l;
    for (int i = tid; i < WHH_Q_SZ / 4; i += 512) dst[i] = src[i];
  }
  // preload h0 into h_l (f16-packed), stage x_0
  {
    int b = tid >> 7, p = tid & 127;
    float2 hv = ((const float2*)h0)[(4 * c + b) * 128 + p];
    h_l[b * 132 + p] = packh2(hv.x, hv.y);
  }
  if (tid < 256) {
    int b = tid >> 6, p = tid & 63;
    int tok = inp[4 * c + b];
    float2 e = ((const float2*)emb)[tok * 64 + p];
    x_l[b * 64 + p] = packh2(e.x, e.y);
  }

  // per-thread state
  float cc[2][4];
  float bz[8];
  int len[4];
#pragma unroll
  for (int up = 0; up < 2; ++up)
#pragma unroll
    for (int b = 0; b < 4; ++b)
      cc[up][b] = c0[(4 * c + b) * HDIM + 64 * q + 2 * rg + up];
#pragma unroll
  for (int j = 0; j < 8; ++j) {
    int g = j >> 1, up = j & 1;
    bz[j] = biasc[g * 256 + 64 * q + 2 * rg + up];
  }
#pragma unroll
  for (int b = 0; b < 4; ++b) len[b] = lengths[4 * c + b] - 1;

  const uint4* wih_t = (const uint4*)wihP + ((q * 32 + rg) * 16 + kq) * 8;

  __syncthreads();

  for (int s = 0; s < S_LEN; ++s) {
    const int par = s & 1;

    // ---- x-part (no dependence on h_{s-1}; hides barrier latency) ----
    uint4 wv[8];
#pragma unroll
    for (int j = 0; j < 8; ++j) wv[j] = wih_t[j];
    uint4 xa[4];
#pragma unroll
    for (int b = 0; b < 4; ++b) xa[b] = *(const uint4*)(x_l + par * 256 + b * 64 + kq * 4);

    float acc[8][4];
#pragma unroll
    for (int j = 0; j < 8; ++j)
#pragma unroll
      for (int b = 0; b < 4; ++b) {
        float a = 0.f;
        a = dot2f(a, wv[j].x, xa[b].x);
        a = dot2f(a, wv[j].y, xa[b].y);
        a = dot2f(a, wv[j].z, xa[b].z);
        a = dot2f(a, wv[j].w, xa[b].w);
        acc[j][b] = a;
      }

    // stage x_{s+1} into the other parity buffer
    if (s + 1 < S_LEN && tid < 256) {
      int b = tid >> 6, p = tid & 63;
      int tok = inp[(s + 1) * BATCH + 4 * c + b];
      float2 e = ((const float2*)emb)[tok * 64 + p];
      x_l[(par ^ 1) * 256 + b * 64 + p] = packh2(e.x, e.y);
    }

    // ---- cluster barrier: wait for peers' h_{s-1} ----
    if (s > 0) {
      if (tid == 0) {
        while (__hip_atomic_load(ctr, __ATOMIC_RELAXED, __HIP_MEMORY_SCOPE_AGENT) < 4 * s)
          __builtin_amdgcn_s_sleep(2);
      }
    }
    __syncthreads();
    if (s > 0) {  // refill h_l from hbuf[(s-1)&1]
      int b = tid >> 7, p = tid & 127;
      uint32 v = __hip_atomic_load(hbuf + (((par ^ 1) * 64 + c) * 4 + b) * 128 + p,
                                   __ATOMIC_RELAXED, __HIP_MEMORY_SCOPE_AGENT);
      h_l[b * 132 + p] = v;
    }
    __syncthreads();

    // ---- h-part: W_hh (LDS) x h (LDS) ----
    uint4 ha[4][2];
#pragma unroll
    for (int b = 0; b < 4; ++b) {
      ha[b][0] = *(const uint4*)(h_l + b * 132 + kq * 8);
      ha[b][1] = *(const uint4*)(h_l + b * 132 + kq * 8 + 4);
    }
#pragma unroll
    for (int j = 0; j < 8; ++j) {
      int g = j >> 1, up = j & 1;
      int rp = g * 64 + up * 32 + rg;
      const uint32* wp = whh_l + rp * 132 + kq * 8;
      uint4 w0 = *(const uint4*)wp;
      uint4 w1 = *(const uint4*)(wp + 4);
#pragma unroll
      for (int b = 0; b < 4; ++b) {
        float a = acc[j][b];
        a = dot2f(a, w0.x, ha[b][0].x); a = dot2f(a, w0.y, ha[b][0].y);
        a = dot2f(a, w0.z, ha[b][0].z); a = dot2f(a, w0.w, ha[b][0].w);
        a = dot2f(a, w1.x, ha[b][1].x); a = dot2f(a, w1.y, ha[b][1].y);
        a = dot2f(a, w1.z, ha[b][1].z); a = dot2f(a, w1.w, ha[b][1].w);
        acc[j][b] = a;
      }
    }

    // ---- k-reduce across the 16 kq lanes (DPP) ----
#pragma unroll
    for (int j = 0; j < 8; ++j)
#pragma unroll
      for (int b = 0; b < 4; ++b) acc[j][b] = rowsum16(acc[j][b]);

    // ---- gate nonlinearities, c/h update, publish (kq==0 lanes) ----
    if (kq == 0) {
#pragma unroll
      for (int b = 0; b < 4; ++b) {
        float hv[2];
#pragma unroll
        for (int up = 0; up < 2; ++up) {
          float iv = sigf(acc[up][b] + bz[up]);
          float fv = sigf(acc[2 + up][b] + bz[2 + up]);
          float gv = tanhfast(acc[4 + up][b] + bz[4 + up]);
          float ov = sigf(acc[6 + up][b] + bz[6 + up]);
          float cn = fv * cc[up][b] + iv * gv;
          cc[up][b] = cn;
          float hn = ov * tanhfast(cn);
          hv[up] = hn;
          if (s == len[b]) {
            outh[(4 * c + b) * HDIM + 64 * q + 2 * rg + up] = hn;
            outc[(4 * c + b) * HDIM + 64 * q + 2 * rg + up] = cn;
          }
        }
        __hip_atomic_store(hbuf + ((par * 64 + c) * 4 + b) * 128 + 32 * q + rg,
                           packh2(hv[0], hv[1]),
                           __ATOMIC_RELAXED, __HIP_MEMORY_SCOPE_AGENT);
      }
    }

    // ---- publish barrier ----
    __threadfence();     // drain this wave's stores (incl. bypass stores) before arrival
    __syncthreads();
    if (tid == 0) atomicAdd(ctr, 1);
  }
}

// ---------------- decode: [B,2] = sigmoid(last_h @ dec_w^T) ----------------
__global__ __launch_bounds__(64) void decode_kernel(const float* __restrict__ outh,
                                                    const float* __restrict__ dec_w,
                                                    float* __restrict__ dec) {
  int b = blockIdx.x, l = threadIdx.x;
  float p0 = 0.f, p1 = 0.f;
#pragma unroll
  for (int m = 0; m < HDIM / 64; ++m) {
    float h = outh[b * HDIM + l + 64 * m];
    p0 = fmaf(h, dec_w[l + 64 * m], p0);
    p1 = fmaf(h, dec_w[HDIM + l + 64 * m], p1);
  }
#pragma unroll
  for (int off = 32; off > 0; off >>= 1) {
    p0 += __shfl_down(p0, off);
    p1 += __shfl_down(p1, off);
  }
  if (l == 0) {
    dec[b * ODIM + 0] = sigf(p0);
    dec[b * ODIM + 1] = sigf(p1);
  }
}

extern "C" void kernel_launch(void* const* d_in, const int* in_sizes, int n_in,
                              void* d_out, int out_size, void* d_ws, size_t ws_size,
                              hipStream_t stream) {
  const int*   inp     = (const int*)d_in[0];
  const int*   lengths = (const int*)d_in[1];
  const float* h0      = (const float*)d_in[2];
  const float* c0      = (const float*)d_in[3];
  const float* emb     = (const float*)d_in[4];
  const float* w_ih    = (const float*)d_in[5];
  const float* w_hh    = (const float*)d_in[6];
  const float* b_ih    = (const float*)d_in[7];
  const float* b_hh    = (const float*)d_in[8];
  const float* dec_w   = (const float*)d_in[9];

  uint32* ws_u = (uint32*)d_ws;

  float* dec  = (float*)d_out;           // [B, 2]
  float* outh = dec + BATCH * ODIM;      // [1, B, H]
  float* outc = outh + BATCH * HDIM;     // [1, B, H]

  const int prep_total = 131072 + 65536 + 1024 + 64;
  prep_kernel<<<(prep_total + 255) / 256, 256, 0, stream>>>(w_ih, w_hh, b_ih, b_hh, ws_u);
  lstm_kernel<<<BATCH / 4 * 4, 512, 0, stream>>>(inp, lengths, h0, c0, emb, ws_u, outh, outc);
  decode_kernel<<<BATCH, 64, 0, stream>>>(outh, dec_w, dec);
}

// Round 3
// 7745.999 us; speedup vs baseline: 4.4844x; 4.4844x over previous
//
#include <hip/hip_runtime.h>
#include <hip/hip_bf16.h>
#include <hip/hip_fp16.h>

// Problem: S,B,E,H,V,O = 1024,256,128,256,32000,2
#define S_LEN 1024
#define BATCH 256
#define EDIM  128
#define HDIM  256
#define ODIM  2

typedef unsigned int uint32;
typedef _Float16 half_t;
typedef half_t half2v __attribute__((ext_vector_type(2)));

// ---------------- ws layout (uint32 units) ----------------
// whhP: [4 q][256 rows'][132]   f16 pairs, LDS image. row' = g*64 + u'*32 + rg
// wihP: [4 q][32 rg][16 kq][8 j][4 pp]
// biasc: 1024 floats
// hbuf: [2 parity][64 cluster][4 b][128 pair]
// flags: [64 cluster][4 member][32]   (128B apart, monotonic step counters)
#define WHH_Q_SZ   (256 * 132)          // 33792
#define OFF_WHH    0
#define OFF_WIH    (4 * WHH_Q_SZ)       // 135168
#define OFF_BIAS   (OFF_WIH + 65536)    // 200704
#define OFF_HBUF   (OFF_BIAS + 1024)    // 201728
#define OFF_FLAG   (OFF_HBUF + 65536)   // 267264
#define N_FLAG     (64 * 4 * 32)        // 8192

__device__ __forceinline__ float sigf(float x)     { return 1.0f / (1.0f + __expf(-x)); }
__device__ __forceinline__ float tanhfast(float x) { return 1.0f - 2.0f / (__expf(2.0f * x) + 1.0f); }

__device__ __forceinline__ uint32 packh2(float a, float b) {
  union { uint32 u; half2v h; } c; c.h[0] = (half_t)a; c.h[1] = (half_t)b; return c.u;
}
__device__ __forceinline__ half2v u2h(uint32 u) {
  union { uint32 u; half2v h; } c; c.u = u; return c.h;
}

#if defined(__has_builtin)
#if __has_builtin(__builtin_amdgcn_fdot2)
#define HAVE_FDOT2 1
#endif
#endif

__device__ __forceinline__ float dot2f(float acc, uint32 w, uint32 x) {
#ifdef HAVE_FDOT2
  return __builtin_amdgcn_fdot2(u2h(w), u2h(x), acc, false);
#else
  half2v a = u2h(w), b = u2h(x);
  acc = fmaf((float)a[0], (float)b[0], acc);
  return fmaf((float)a[1], (float)b[1], acc);
#endif
}

// sum across the 16-lane DPP row; all 16 lanes receive the total
__device__ __forceinline__ float rowsum16(float v) {
  v += __int_as_float(__builtin_amdgcn_update_dpp(0, __float_as_int(v), 0x128, 0xf, 0xf, true)); // row_ror:8
  v += __int_as_float(__builtin_amdgcn_update_dpp(0, __float_as_int(v), 0x124, 0xf, 0xf, true)); // row_ror:4
  v += __int_as_float(__builtin_amdgcn_update_dpp(0, __float_as_int(v), 0x122, 0xf, 0xf, true)); // row_ror:2
  v += __int_as_float(__builtin_amdgcn_update_dpp(0, __float_as_int(v), 0x121, 0xf, 0xf, true)); // row_ror:1
  return v;
}

// ---------------- prep: pack weights f16, fold bias, zero flags ----------------
__global__ void prep_kernel(const float* __restrict__ w_ih, const float* __restrict__ w_hh,
                            const float* __restrict__ b_ih, const float* __restrict__ b_hh,
                            uint32* __restrict__ ws_u) {
  uint32* whhP = ws_u + OFF_WHH;
  uint32* wihP = ws_u + OFF_WIH;
  float*  biasc = (float*)(ws_u + OFF_BIAS);
  int*    flags = (int*)(ws_u + OFF_FLAG);
  int id = blockIdx.x * 256 + threadIdx.x;
  if (id < 131072) {                          // whh: 4q * 256r * 128p
    int q = id >> 15, rem = id & 32767;
    int r = rem >> 7, p = rem & 127;
    int g = r >> 6, lu = r & 63;
    int rp = g * 64 + (lu & 1) * 32 + (lu >> 1);
    int orig = g * 256 + q * 64 + lu;
    whhP[q * WHH_Q_SZ + rp * 132 + p] = packh2(w_hh[orig * HDIM + 2 * p], w_hh[orig * HDIM + 2 * p + 1]);
  } else if (id < 131072 + 65536) {           // wih
    int id2 = id - 131072;
    int q = id2 >> 14, rem = id2 & 16383;
    int rg = rem >> 9, kq = (rem >> 5) & 15, j = (rem >> 2) & 7, pp = rem & 3;
    int g = j >> 1, up = j & 1;
    int lu = 2 * rg + up;
    int orig = g * 256 + q * 64 + lu;
    int k = (kq * 4 + pp) * 2;
    wihP[(((q * 32 + rg) * 16 + kq) * 8 + j) * 4 + pp] =
        packh2(w_ih[orig * EDIM + k], w_ih[orig * EDIM + k + 1]);
  } else if (id < 131072 + 65536 + 1024) {
    int i = id - 131072 - 65536;
    biasc[i] = b_ih[i] + b_hh[i];
  } else if (id < 131072 + 65536 + 1024 + N_FLAG) {
    flags[id - 131072 - 65536 - 1024] = 0;
  }
}

// ---------------- LSTM: 4-block same-XCD clusters, LDS-resident W_hh ----------------
// member q = bid>>6 (hidden units 64q..64q+64), cluster c = bid&63 (batch cols 4c..4c+3).
// Members {c, c+64, c+128, c+192} are all == c (mod 8) -> same XCD under round-robin
// dispatch (latency heuristic; correctness comes from agent-scope atomics).
// thread: rg = tid>>4 (unit pair 2rg,2rg+1), kq = tid&15 (k-slice). DPP row == one rg's 16 kq lanes.
__global__ __launch_bounds__(512, 2) void lstm_kernel(
    const int* __restrict__ inp, const int* __restrict__ lengths,
    const float* __restrict__ h0, const float* __restrict__ c0,
    const float* __restrict__ emb, uint32* __restrict__ ws_u,
    float* __restrict__ outh, float* __restrict__ outc) {
  __shared__ uint32 whh_l[WHH_Q_SZ];     // 135168 B
  __shared__ uint32 h_l[4 * 132];        // [b][pair], stride 132
  __shared__ uint32 x_l[2 * 256];        // [parity][b][pair(64)]

  const int tid = threadIdx.x;
  const int q = blockIdx.x >> 6;         // member / hidden slice
  const int c = blockIdx.x & 63;         // cluster
  const int rg = tid >> 4, kq = tid & 15;

  const uint32* whhP = ws_u + OFF_WHH + q * WHH_Q_SZ;
  const uint32* wihP = ws_u + OFF_WIH;
  const float*  biasc = (const float*)(ws_u + OFF_BIAS);
  uint32* hbuf = ws_u + OFF_HBUF;
  int*    flags = (int*)(ws_u + OFF_FLAG);
  int*    myflag = flags + (c * 4 + q) * 32;

  // load W_hh slice into LDS (once)
  {
    const uint4* src = (const uint4*)whhP;
    uint4* dst = (uint4*)whh_l;
    for (int i = tid; i < WHH_Q_SZ / 4; i += 512) dst[i] = src[i];
  }
  // preload h0 into h_l (f16-packed), stage x_0
  {
    int b = tid >> 7, p = tid & 127;
    float2 hv = ((const float2*)h0)[(4 * c + b) * 128 + p];
    h_l[b * 132 + p] = packh2(hv.x, hv.y);
  }
  if (tid < 256) {
    int b = tid >> 6, p = tid & 63;
    int tok = inp[4 * c + b];
    float2 e = ((const float2*)emb)[tok * 64 + p];
    x_l[b * 64 + p] = packh2(e.x, e.y);
  }

  // per-thread state
  float cc[2][4];
  float bz[8];
  int len[4];
#pragma unroll
  for (int up = 0; up < 2; ++up)
#pragma unroll
    for (int b = 0; b < 4; ++b)
      cc[up][b] = c0[(4 * c + b) * HDIM + 64 * q + 2 * rg + up];
#pragma unroll
  for (int j = 0; j < 8; ++j) {
    int g = j >> 1, up = j & 1;
    bz[j] = biasc[g * 256 + 64 * q + 2 * rg + up];
  }
#pragma unroll
  for (int b = 0; b < 4; ++b) len[b] = lengths[4 * c + b] - 1;

  const uint4* wih_t = (const uint4*)wihP + ((q * 32 + rg) * 16 + kq) * 8;

  __syncthreads();

  for (int s = 0; s < S_LEN; ++s) {
    const int par = s & 1;

    // ---- x-part (no dependence on h_{s-1}; overlaps peer-wait) ----
    uint4 wv[8];
#pragma unroll
    for (int j = 0; j < 8; ++j) wv[j] = wih_t[j];
    uint4 xa[4];
#pragma unroll
    for (int b = 0; b < 4; ++b) xa[b] = *(const uint4*)(x_l + par * 256 + b * 64 + kq * 4);

    float acc[8][4];
#pragma unroll
    for (int j = 0; j < 8; ++j)
#pragma unroll
      for (int b = 0; b < 4; ++b) {
        float a = 0.f;
        a = dot2f(a, wv[j].x, xa[b].x);
        a = dot2f(a, wv[j].y, xa[b].y);
        a = dot2f(a, wv[j].z, xa[b].z);
        a = dot2f(a, wv[j].w, xa[b].w);
        acc[j][b] = a;
      }

    // stage x_{s+1} into the other parity buffer (normal cached loads; no fences
    // anywhere in this kernel, so emb/wih stay L2-resident)
    if (s + 1 < S_LEN && tid < 256) {
      int b = tid >> 6, p = tid & 63;
      int tok = inp[(s + 1) * BATCH + 4 * c + b];
      float2 e = ((const float2*)emb)[tok * 64 + p];
      x_l[(par ^ 1) * 256 + b * 64 + p] = packh2(e.x, e.y);
    }

    // ---- wait for 3 peers' h_{s-1}: lanes 0..2 poll one peer flag each ----
    if (s > 0) {
      if (tid < 3) {
        int peer = tid + (tid >= q ? 1 : 0);
        int* fl = flags + (c * 4 + peer) * 32;
        // relaxed agent-scope spin; monotonic counter, no RMW, 128B-isolated line
        while (__hip_atomic_load(fl, __ATOMIC_RELAXED, __HIP_MEMORY_SCOPE_AGENT) < s) { }
      }
      __syncthreads();   // compiler+exec barrier: hbuf reads below issue after flags confirmed
      {
        int b = tid >> 7, p = tid & 127;
        uint32 v = __hip_atomic_load(hbuf + (((par ^ 1) * 64 + c) * 4 + b) * 128 + p,
                                     __ATOMIC_RELAXED, __HIP_MEMORY_SCOPE_AGENT);
        h_l[b * 132 + p] = v;
      }
      __syncthreads();
    }

    // ---- h-part: W_hh (LDS) x h (LDS) ----
    uint4 ha[4][2];
#pragma unroll
    for (int b = 0; b < 4; ++b) {
      ha[b][0] = *(const uint4*)(h_l + b * 132 + kq * 8);
      ha[b][1] = *(const uint4*)(h_l + b * 132 + kq * 8 + 4);
    }
#pragma unroll
    for (int j = 0; j < 8; ++j) {
      int g = j >> 1, up = j & 1;
      int rp = g * 64 + up * 32 + rg;
      const uint32* wp = whh_l + rp * 132 + kq * 8;
      uint4 w0 = *(const uint4*)wp;
      uint4 w1 = *(const uint4*)(wp + 4);
#pragma unroll
      for (int b = 0; b < 4; ++b) {
        float a = acc[j][b];
        a = dot2f(a, w0.x, ha[b][0].x); a = dot2f(a, w0.y, ha[b][0].y);
        a = dot2f(a, w0.z, ha[b][0].z); a = dot2f(a, w0.w, ha[b][0].w);
        a = dot2f(a, w1.x, ha[b][1].x); a = dot2f(a, w1.y, ha[b][1].y);
        a = dot2f(a, w1.z, ha[b][1].z); a = dot2f(a, w1.w, ha[b][1].w);
        acc[j][b] = a;
      }
    }

    // ---- k-reduce across the 16 kq lanes (DPP) ----
#pragma unroll
    for (int j = 0; j < 8; ++j)
#pragma unroll
      for (int b = 0; b < 4; ++b) acc[j][b] = rowsum16(acc[j][b]);

    // ---- gate nonlinearities, c/h update, publish data (kq==0 lanes) ----
    if (kq == 0) {
#pragma unroll
      for (int b = 0; b < 4; ++b) {
        float hv[2];
#pragma unroll
        for (int up = 0; up < 2; ++up) {
          float iv = sigf(acc[up][b] + bz[up]);
          float fv = sigf(acc[2 + up][b] + bz[2 + up]);
          float gv = tanhfast(acc[4 + up][b] + bz[4 + up]);
          float ov = sigf(acc[6 + up][b] + bz[6 + up]);
          float cn = fv * cc[up][b] + iv * gv;
          cc[up][b] = cn;
          float hn = ov * tanhfast(cn);
          hv[up] = hn;
          if (s == len[b]) {
            outh[(4 * c + b) * HDIM + 64 * q + 2 * rg + up] = hn;
            outc[(4 * c + b) * HDIM + 64 * q + 2 * rg + up] = cn;
          }
        }
        __hip_atomic_store(hbuf + ((par * 64 + c) * 4 + b) * 128 + 32 * q + rg,
                           packh2(hv[0], hv[1]),
                           __ATOMIC_RELAXED, __HIP_MEMORY_SCOPE_AGENT);
      }
    }

    // ---- publish flag: __syncthreads drains vmcnt(0) (compiler emits it before
    // s_barrier), so all members' data stores are at the coherence point before
    // tid0's in-order flag store issues. No fence, no wbl2, no inv. ----
    __syncthreads();
    if (tid == 0)
      __hip_atomic_store(myflag, s + 1, __ATOMIC_RELAXED, __HIP_MEMORY_SCOPE_AGENT);
  }
}

// ---------------- decode: [B,2] = sigmoid(last_h @ dec_w^T) ----------------
__global__ __launch_bounds__(64) void decode_kernel(const float* __restrict__ outh,
                                                    const float* __restrict__ dec_w,
                                                    float* __restrict__ dec) {
  int b = blockIdx.x, l = threadIdx.x;
  float p0 = 0.f, p1 = 0.f;
#pragma unroll
  for (int m = 0; m < HDIM / 64; ++m) {
    float h = outh[b * HDIM + l + 64 * m];
    p0 = fmaf(h, dec_w[l + 64 * m], p0);
    p1 = fmaf(h, dec_w[HDIM + l + 64 * m], p1);
  }
#pragma unroll
  for (int off = 32; off > 0; off >>= 1) {
    p0 += __shfl_down(p0, off);
    p1 += __shfl_down(p1, off);
  }
  if (l == 0) {
    dec[b * ODIM + 0] = sigf(p0);
    dec[b * ODIM + 1] = sigf(p1);
  }
}

extern "C" void kernel_launch(void* const* d_in, const int* in_sizes, int n_in,
                              void* d_out, int out_size, void* d_ws, size_t ws_size,
                              hipStream_t stream) {
  const int*   inp     = (const int*)d_in[0];
  const int*   lengths = (const int*)d_in[1];
  const float* h0      = (const float*)d_in[2];
  const float* c0      = (const float*)d_in[3];
  const float* emb     = (const float*)d_in[4];
  const float* w_ih    = (const float*)d_in[5];
  const float* w_hh    = (const float*)d_in[6];
  const float* b_ih    = (const float*)d_in[7];
  const float* b_hh    = (const float*)d_in[8];
  const float* dec_w   = (const float*)d_in[9];

  uint32* ws_u = (uint32*)d_ws;

  float* dec  = (float*)d_out;           // [B, 2]
  float* outh = dec + BATCH * ODIM;      // [1, B, H]
  float* outc = outh + BATCH * HDIM;     // [1, B, H]

  const int prep_total = 131072 + 65536 + 1024 + N_FLAG;
  prep_kernel<<<(prep_total + 255) / 256, 256, 0, stream>>>(w_ih, w_hh, b_ih, b_hh, ws_u);
  lstm_kernel<<<256, 512, 0, stream>>>(inp, lengths, h0, c0, emb, ws_u, outh, outc);
  decode_kernel<<<BATCH, 64, 0, stream>>>(outh, dec_w, dec);
}

// Round 4
// 3167.554 us; speedup vs baseline: 10.9662x; 2.4454x over previous
//
#include <hip/hip_runtime.h>
#include <hip/hip_bf16.h>
#include <hip/hip_fp16.h>

// Problem: S,B,E,H,V,O = 1024,256,128,256,32000,2
#define S_LEN 1024
#define BATCH 256
#define EDIM  128
#define HDIM  256
#define ODIM  2

typedef unsigned int uint32;
typedef _Float16 half_t;
typedef half_t half2v __attribute__((ext_vector_type(2)));
typedef half_t half8  __attribute__((ext_vector_type(8)));
typedef float  f32x4  __attribute__((ext_vector_type(4)));

// ---------------- ws layout (uint32 units) ----------------
// whhf: MFMA A-fragments of W_hh, [4 q][16 T][8 t][64 lane][4 dw]  (f16 pairs)
// wihf: MFMA A-fragments of W_ih, [4 q][16 T][4 t][64 lane][4 dw]
// hbuf: [2 parity][16 cluster][16 b][128 dw]  (h as f16 pairs, u-major)
// flags:[16 cluster][4 member][32]  (128B-isolated monotonic step counters)
#define OFF_WHHF   0
#define OFF_WIHF   131072
#define OFF_HBUF   196608
#define OFF_FLAG   262144
#define N_FLAG     2048

__device__ __forceinline__ float sigf(float x)     { return 1.0f / (1.0f + __expf(-x)); }
__device__ __forceinline__ float tanhfast(float x) { return 1.0f - 2.0f / (__expf(2.0f * x) + 1.0f); }

__device__ __forceinline__ uint32 packh2(float a, float b) {
  union { uint32 u; half2v h; } c; c.h[0] = (half_t)a; c.h[1] = (half_t)b; return c.u;
}
__device__ __forceinline__ half8 as_h8(uint4 v) {
  union { uint4 u; half8 h; } c; c.u = v; return c.h;
}
__device__ __forceinline__ unsigned short f16bits(float f) {
  union { half_t h; unsigned short s; } c; c.h = (half_t)f; return c.s;
}

// ---------------- prep: pack W into per-lane MFMA A-fragment order ----------------
// A-layout (16x16x32): lane l holds A[m = l&15][k = (l>>4)*8 + j], j=0..7 (f16 pairs in 4 dwords).
// Block q owns hidden units 64q..64q+63; tile T: gate g=T>>2, unit sub-block T&3.
// grow(T,l) = (T>>2)*256 + q*64 + (T&3)*16 + (l&15).
__global__ void prep_kernel(const float* __restrict__ w_ih, const float* __restrict__ w_hh,
                            uint32* __restrict__ ws_u) {
  int id = blockIdx.x * 256 + threadIdx.x;
  if (id < 131072) {                     // whhf dwords: [q][T][t(8)][l][d]
    int q = id >> 15, T = (id >> 11) & 15, t = (id >> 8) & 7, l = (id >> 2) & 63, d = id & 3;
    int grow = (T >> 2) * 256 + q * 64 + (T & 3) * 16 + (l & 15);
    int k = t * 32 + (l >> 4) * 8 + 2 * d;
    ws_u[OFF_WHHF + id] = packh2(w_hh[grow * HDIM + k], w_hh[grow * HDIM + k + 1]);
  } else if (id < 131072 + 65536) {      // wihf dwords: [q][T][t(4)][l][d]
    int i2 = id - 131072;
    int q = i2 >> 14, T = (i2 >> 10) & 15, t = (i2 >> 8) & 3, l = (i2 >> 2) & 63, d = i2 & 3;
    int grow = (T >> 2) * 256 + q * 64 + (T & 3) * 16 + (l & 15);
    int k = t * 32 + (l >> 4) * 8 + 2 * d;
    ws_u[OFF_WIHF + i2] = packh2(w_ih[grow * EDIM + k], w_ih[grow * EDIM + k + 1]);
  } else if (id < 131072 + 65536 + N_FLAG) {
    ((int*)(ws_u + OFF_FLAG))[id - 131072 - 65536] = 0;
  }
}

// ---------------- LSTM: MFMA recurrence, register-resident weights ----------------
// 16 clusters x 4 members = 64 blocks. Cluster c: batch cols 16c..16c+15.
// Member q = bid>>4: hidden units 64q..64q+63 (gate rows g*256+64q+[0,64) for g=0..3).
// bid = q*16+c -> members {c,16+c,32+c,48+c} == c (mod 8): same XCD (heuristic only).
// 512 threads = 8 waves; wave w owns row-tiles T=2w,2w+1; weights held as A-frags in VGPRs.
__global__ __launch_bounds__(512, 2) void lstm_kernel(
    const int* __restrict__ inp, const int* __restrict__ lengths,
    const float* __restrict__ h0, const float* __restrict__ c0,
    const float* __restrict__ emb,
    const float* __restrict__ b_ih, const float* __restrict__ b_hh,
    uint32* __restrict__ ws_u,
    float* __restrict__ outh, float* __restrict__ outc) {
  __shared__ uint32 x_l[2 * 16 * 68];   // [parity][b][64 dw + pad4]  x as f16 pairs
  __shared__ uint32 h_l[16 * 132];      // [b][128 dw + pad4]         h as f16 pairs
  __shared__ float  gbuf[16 * 16 * 20]; // [T][row16][16 cols + pad4] fp32 gates

  const int tid  = threadIdx.x;
  const int lane = tid & 63, w = tid >> 6;
  const int c = blockIdx.x & 15, q = blockIdx.x >> 4;
  const int n = lane & 15, p = lane >> 4;   // MFMA col / quad
  const int bb = tid >> 5, kk = tid & 31;   // staging map
  const int ub = tid >> 4, b = tid & 15;    // epilogue map: units ub, ub+32; col b

  unsigned short* hb16 = (unsigned short*)(ws_u + OFF_HBUF);
  int* flags  = (int*)(ws_u + OFF_FLAG);
  int* myflag = flags + (c * 4 + q) * 32;

  // ---- load weight A-fragments into registers (persistent) ----
  uint4 ahh[2][8], aih[2][4];
  {
    const uint4* whhf = (const uint4*)(ws_u + OFF_WHHF);
    const uint4* wihf = (const uint4*)(ws_u + OFF_WIHF);
#pragma unroll
    for (int T2 = 0; T2 < 2; ++T2) {
      int T = 2 * w + T2;
#pragma unroll
      for (int t = 0; t < 8; ++t) ahh[T2][t] = whhf[((q * 16 + T) * 8 + t) * 64 + lane];
#pragma unroll
      for (int t = 0; t < 4; ++t) aih[T2][t] = wihf[((q * 16 + T) * 4 + t) * 64 + lane];
    }
  }

  // ---- per-thread epilogue state ----
  float bias_[2][4], cst[2];
  const int len = lengths[16 * c + b] - 1;
#pragma unroll
  for (int pp = 0; pp < 2; ++pp) {
    int u = ub + 32 * pp;
#pragma unroll
    for (int g = 0; g < 4; ++g) {
      int grow = g * 256 + q * 64 + u;
      bias_[pp][g] = b_ih[grow] + b_hh[grow];
    }
    cst[pp] = c0[(16 * c + b) * HDIM + q * 64 + u];
  }

  // ---- prologue staging: h0 -> h_l, x_0 -> x_l[0] ----
  {
    const float2* src = (const float2*)h0 + (16 * c + bb) * 128 + kk * 4;
    float2 v0 = src[0], v1 = src[1], v2 = src[2], v3 = src[3];
    uint4 pk = { packh2(v0.x, v0.y), packh2(v1.x, v1.y), packh2(v2.x, v2.y), packh2(v3.x, v3.y) };
    *(uint4*)(h_l + bb * 132 + kk * 4) = pk;
  }
  if (kk < 16) {
    int tok = inp[16 * c + bb];
    const float2* src = (const float2*)emb + tok * 64 + kk * 4;
    float2 v0 = src[0], v1 = src[1], v2 = src[2], v3 = src[3];
    uint4 pk = { packh2(v0.x, v0.y), packh2(v1.x, v1.y), packh2(v2.x, v2.y), packh2(v3.x, v3.y) };
    *(uint4*)(x_l + bb * 68 + kk * 4) = pk;
  }
  __syncthreads();

  for (int s = 0; s < S_LEN; ++s) {
    const int par = s & 1;

    // ---- phase 1: x-part MFMA (independent of h_{s-1}; overlaps peer wait) ----
    f32x4 acc0 = {0.f, 0.f, 0.f, 0.f}, acc1 = {0.f, 0.f, 0.f, 0.f};
#pragma unroll
    for (int t = 0; t < 4; ++t) {
      uint4 xb = *(const uint4*)(x_l + par * 1088 + n * 68 + t * 16 + p * 4);
      acc0 = __builtin_amdgcn_mfma_f32_16x16x32_f16(as_h8(aih[0][t]), as_h8(xb), acc0, 0, 0, 0);
      acc1 = __builtin_amdgcn_mfma_f32_16x16x32_f16(as_h8(aih[1][t]), as_h8(xb), acc1, 0, 0, 0);
    }

    // ---- phase 2: stage x_{s+1} into other parity ----
    if (s + 1 < S_LEN && kk < 16) {
      int tok = inp[(s + 1) * BATCH + 16 * c + bb];
      const float2* src = (const float2*)emb + tok * 64 + kk * 4;
      float2 v0 = src[0], v1 = src[1], v2 = src[2], v3 = src[3];
      uint4 pk = { packh2(v0.x, v0.y), packh2(v1.x, v1.y), packh2(v2.x, v2.y), packh2(v3.x, v3.y) };
      *(uint4*)(x_l + (par ^ 1) * 1088 + bb * 68 + kk * 4) = pk;
    }

    // ---- phase 3: wait for 3 peers' h_{s-1} ----
    if (s > 0 && tid < 3) {
      int peer = tid + (tid >= q ? 1 : 0);
      const int* fl = flags + (c * 4 + peer) * 32;
      while (__hip_atomic_load(fl, __ATOMIC_RELAXED, __HIP_MEMORY_SCOPE_AGENT) < s) { }
    }
    __syncthreads();   // B1: flag confirmed before any hbuf read issues

    // ---- phase 5: hbuf -> h_l (s==0: h_l holds h0 from prologue) ----
    if (s > 0) {
      const uint32* hbd = ws_u + OFF_HBUF + (((par ^ 1) * 16 + c) * 16 + bb) * 128 + kk * 4;
      uint4 v;
      v.x = __hip_atomic_load(hbd + 0, __ATOMIC_RELAXED, __HIP_MEMORY_SCOPE_AGENT);
      v.y = __hip_atomic_load(hbd + 1, __ATOMIC_RELAXED, __HIP_MEMORY_SCOPE_AGENT);
      v.z = __hip_atomic_load(hbd + 2, __ATOMIC_RELAXED, __HIP_MEMORY_SCOPE_AGENT);
      v.w = __hip_atomic_load(hbd + 3, __ATOMIC_RELAXED, __HIP_MEMORY_SCOPE_AGENT);
      *(uint4*)(h_l + bb * 132 + kk * 4) = v;
    }
    __syncthreads();   // B2

    // ---- phase 7: h-part MFMA ----
#pragma unroll
    for (int t = 0; t < 8; ++t) {
      uint4 hbv = *(const uint4*)(h_l + n * 132 + t * 16 + p * 4);
      acc0 = __builtin_amdgcn_mfma_f32_16x16x32_f16(as_h8(ahh[0][t]), as_h8(hbv), acc0, 0, 0, 0);
      acc1 = __builtin_amdgcn_mfma_f32_16x16x32_f16(as_h8(ahh[1][t]), as_h8(hbv), acc1, 0, 0, 0);
    }

    // ---- phase 8a: C -> gbuf (D layout: row = p*4+r, col = n) ----
#pragma unroll
    for (int r = 0; r < 4; ++r) {
      gbuf[(2 * w) * 320 + (p * 4 + r) * 20 + n]     = acc0[r];
      gbuf[(2 * w + 1) * 320 + (p * 4 + r) * 20 + n] = acc1[r];
    }
    __syncthreads();   // B3

    // ---- phase 8c: gate math, c/h update, publish h (f16) ----
#pragma unroll
    for (int pp = 0; pp < 2; ++pp) {
      int u = ub + 32 * pp;
      int Tb = u >> 4, ur = u & 15;
      float gi = gbuf[(0  + Tb) * 320 + ur * 20 + b] + bias_[pp][0];
      float gf = gbuf[(4  + Tb) * 320 + ur * 20 + b] + bias_[pp][1];
      float gg = gbuf[(8  + Tb) * 320 + ur * 20 + b] + bias_[pp][2];
      float go = gbuf[(12 + Tb) * 320 + ur * 20 + b] + bias_[pp][3];
      float iv = sigf(gi), fv = sigf(gf), gv = tanhfast(gg), ov = sigf(go);
      float cn = fv * cst[pp] + iv * gv;
      cst[pp] = cn;
      float hn = ov * tanhfast(cn);
      if (s == len) {
        outh[(16 * c + b) * HDIM + q * 64 + u] = hn;
        outc[(16 * c + b) * HDIM + q * 64 + u] = cn;
      }
      hb16[((par * 16 + c) * 16 + b) * 256 + q * 64 + u] = f16bits(hn);
    }

    // ---- B4 + flag: syncthreads drains vmcnt(0) (all members' h stores at L2)
    // before tid0's in-order flag store. Same protocol as R3 (verified). ----
    __syncthreads();
    if (tid == 0)
      __hip_atomic_store(myflag, s + 1, __ATOMIC_RELAXED, __HIP_MEMORY_SCOPE_AGENT);
  }
}

// ---------------- decode: [B,2] = sigmoid(last_h @ dec_w^T) ----------------
__global__ __launch_bounds__(64) void decode_kernel(const float* __restrict__ outh,
                                                    const float* __restrict__ dec_w,
                                                    float* __restrict__ dec) {
  int b = blockIdx.x, l = threadIdx.x;
  float p0 = 0.f, p1 = 0.f;
#pragma unroll
  for (int m = 0; m < HDIM / 64; ++m) {
    float h = outh[b * HDIM + l + 64 * m];
    p0 = fmaf(h, dec_w[l + 64 * m], p0);
    p1 = fmaf(h, dec_w[HDIM + l + 64 * m], p1);
  }
#pragma unroll
  for (int off = 32; off > 0; off >>= 1) {
    p0 += __shfl_down(p0, off);
    p1 += __shfl_down(p1, off);
  }
  if (l == 0) {
    dec[b * ODIM + 0] = sigf(p0);
    dec[b * ODIM + 1] = sigf(p1);
  }
}

extern "C" void kernel_launch(void* const* d_in, const int* in_sizes, int n_in,
                              void* d_out, int out_size, void* d_ws, size_t ws_size,
                              hipStream_t stream) {
  const int*   inp     = (const int*)d_in[0];
  const int*   lengths = (const int*)d_in[1];
  const float* h0      = (const float*)d_in[2];
  const float* c0      = (const float*)d_in[3];
  const float* emb     = (const float*)d_in[4];
  const float* w_ih    = (const float*)d_in[5];
  const float* w_hh    = (const float*)d_in[6];
  const float* b_ih    = (const float*)d_in[7];
  const float* b_hh    = (const float*)d_in[8];
  const float* dec_w   = (const float*)d_in[9];

  uint32* ws_u = (uint32*)d_ws;

  float* dec  = (float*)d_out;           // [B, 2]
  float* outh = dec + BATCH * ODIM;      // [1, B, H]
  float* outc = outh + BATCH * HDIM;     // [1, B, H]

  const int prep_total = 131072 + 65536 + N_FLAG;
  prep_kernel<<<(prep_total + 255) / 256, 256, 0, stream>>>(w_ih, w_hh, ws_u);
  lstm_kernel<<<64, 512, 0, stream>>>(inp, lengths, h0, c0, emb, b_ih, b_hh,
                                      ws_u, outh, outc);
  decode_kernel<<<BATCH, 64, 0, stream>>>(outh, dec_w, dec);
}